// Round 3
// baseline (549.048 us; speedup 1.0000x reference)
//
#include <hip/hip_runtime.h>
#include <hip/hip_bf16.h>
#include <stdint.h>

// SelfAttention: B=8, N=2048, D=DQ=DV=1024, fp32 in/out, fp16 MFMA internally.
// (Round 2 -> 3: bf16 -> fp16. bf16's 8-bit mantissa gave absmax 0.135 > 0.064;
//  fp16's 11-bit mantissa cuts logit noise 4x at identical MFMA rate.)
//
// Workspace layout (224 MiB total; overlap exploits buffer lifetimes):
//   [0        , 32 MiB)   Q   (fp16)
//   [32 MiB   , 64 MiB)   K   (fp16)
//   [64 MiB   , 96 MiB)   Vt  (fp16, [b*1024+dv][seq])
//   [96 MiB   , 224 MiB)  S   (fp32, 8x2048x2048) -- written AFTER xh/Wt die
//     xh  (fp16 cast of x, 32 MiB) at S base
//     WqT/WkT/WvT (fp16, 2 MiB each) right after xh
//
// Pipeline:
//   1. cast x -> xh ; transpose+cast W* -> W*T
//   2. gemm_bt<0>: Q = xh@WqT+bq ; K = xh@WkT+bk (fp16)
//      gemm_bt<2>: Vt = (xh@WvT+bv)^T per batch  (fp16)
//   3. gemm_bt<1>: S[b] = Q[b]@K[b]^T (fp32)  [overwrites xh/Wt - dead]
//   4. softmax_rows: P = softmax(S) rows, fp16 in place (row base, stride 4096)
//   5. gemm_bt<1>: out[b] = P[b]@Vt[b]^T (fp32 -> d_out)

typedef _Float16 f16;
typedef _Float16 f16x8 __attribute__((ext_vector_type(8)));
typedef _Float16 f16x4 __attribute__((ext_vector_type(4)));
typedef float f32x4 __attribute__((ext_vector_type(4)));

typedef __attribute__((address_space(3))) void lds_void;
typedef const __attribute__((address_space(1))) void gbl_void;

__device__ __forceinline__ void async16(void* l, const void* g) {
    __builtin_amdgcn_global_load_lds(
        reinterpret_cast<gbl_void*>(reinterpret_cast<uintptr_t>(g)),
        reinterpret_cast<lds_void*>(reinterpret_cast<uintptr_t>(l)),
        16, 0, 0);
}

// ---------------------------------------------------------------- cast x
__global__ __launch_bounds__(256) void cast_f32_f16(const float* __restrict__ x,
                                                    f16* __restrict__ y) {
    long i = (long)blockIdx.x * 256 + threadIdx.x;
    float4 v = reinterpret_cast<const float4*>(x)[i];
    f16x4 o = {(f16)v.x, (f16)v.y, (f16)v.z, (f16)v.w};
    reinterpret_cast<f16x4*>(y)[i] = o;
}

// ------------------------------------------------- transpose + cast W -> Wt
__global__ __launch_bounds__(256) void transpose_cast(const float* __restrict__ W,
                                                      f16* __restrict__ Wt,
                                                      int R, int C) {
    __shared__ float tile[32][33];
    int c0 = blockIdx.x * 32, r0 = blockIdx.y * 32;
    int tx = threadIdx.x, ty = threadIdx.y;
#pragma unroll
    for (int i = ty; i < 32; i += 8) tile[i][tx] = W[(long)(r0 + i) * C + c0 + tx];
    __syncthreads();
#pragma unroll
    for (int i = ty; i < 32; i += 8) Wt[(long)(c0 + i) * R + r0 + tx] = (f16)tile[tx][i];
}

// ---------------------------------------------------------------- GEMM
// C[m][n] = sum_k A[m][k] * Bt[n][k]  (+ bias[n])
// OM: 0 = fp16 row-major, 1 = fp32 row-major, 2 = fp16 V-transpose store
//     (OM2: row = b*2048 + seq, out[(b*1024 + n)*2048 + seq])
template <int OM>
__global__ __launch_bounds__(256) void gemm_bt(
    const f16* __restrict__ A, long sA, int lda,
    const f16* __restrict__ Bt, long sB, int ldb,
    const float* __restrict__ bias,
    void* __restrict__ out, long sO, int ldo, int K) {
    __shared__ f16 As[128 * 64];
    __shared__ f16 Bs[128 * 64];
    const int tid = threadIdx.x;
    const int lane = tid & 63;
    const int wv = tid >> 6;
    const int wm = (wv >> 1) * 64;
    const int wn = (wv & 1) * 64;
    const long mBase = (long)blockIdx.y * 128;
    const long nBase = (long)blockIdx.x * 128;
    A += (long)blockIdx.z * sA;
    Bt += (long)blockIdx.z * sB;

    f32x4 acc[4][4] = {};

    for (int k0 = 0; k0 < K; k0 += 64) {
#pragma unroll
        for (int i = 0; i < 4; ++i) {
            int u = i * 256 + tid;
            int r = u >> 3, c = (u & 7) * 8;
            async16((char*)As + u * 16, A + (mBase + r) * (long)lda + k0 + c);
            async16((char*)Bs + u * 16, Bt + (nBase + r) * (long)ldb + k0 + c);
        }
        __syncthreads();
#pragma unroll
        for (int ks = 0; ks < 2; ++ks) {
            f16x8 af[4], bfr[4];
            const int q8 = (lane >> 4) * 8 + ks * 32;
            const int ra = wm + (lane & 15);
            const int rb = wn + (lane & 15);
#pragma unroll
            for (int t = 0; t < 4; ++t) {
                af[t] = *reinterpret_cast<const f16x8*>(&As[(ra + t * 16) * 64 + q8]);
                bfr[t] = *reinterpret_cast<const f16x8*>(&Bs[(rb + t * 16) * 64 + q8]);
            }
#pragma unroll
            for (int am = 0; am < 4; ++am)
#pragma unroll
                for (int an = 0; an < 4; ++an)
                    acc[am][an] = __builtin_amdgcn_mfma_f32_16x16x32_f16(
                        af[am], bfr[an], acc[am][an], 0, 0, 0);
        }
        __syncthreads();
    }

    const int rq = (lane >> 4) * 4;
    const int cl = lane & 15;
#pragma unroll
    for (int am = 0; am < 4; ++am) {
#pragma unroll
        for (int an = 0; an < 4; ++an) {
            long col = nBase + wn + an * 16 + cl;
            float bv = bias ? bias[col] : 0.0f;
#pragma unroll
            for (int r = 0; r < 4; ++r) {
                long row = mBase + wm + am * 16 + rq + r;
                float v = acc[am][an][r] + bv;
                if (OM == 0) {
                    ((f16*)out)[(long)blockIdx.z * sO + row * ldo + col] = (f16)v;
                } else if (OM == 1) {
                    ((float*)out)[(long)blockIdx.z * sO + row * ldo + col] = v;
                } else {
                    long bb = row >> 11, seq = row & 2047;
                    ((f16*)out)[(bb * 1024 + col) * 2048 + seq] = (f16)v;
                }
            }
        }
    }
}

// ---------------------------------------------------------------- softmax
// One block per row of S (16384 rows x 2048 fp32). Writes fp16 P in place.
__global__ __launch_bounds__(256) void softmax_rows(float* __restrict__ S) {
    const long row = blockIdx.x;
    float* rp = S + row * 2048;
    const int t = threadIdx.x;
    float4 v0 = reinterpret_cast<const float4*>(rp)[t * 2];
    float4 v1 = reinterpret_cast<const float4*>(rp)[t * 2 + 1];
    float m = fmaxf(fmaxf(fmaxf(v0.x, v0.y), fmaxf(v0.z, v0.w)),
                    fmaxf(fmaxf(v1.x, v1.y), fmaxf(v1.z, v1.w)));
#pragma unroll
    for (int o = 32; o > 0; o >>= 1) m = fmaxf(m, __shfl_down(m, o, 64));
    __shared__ float red[8];
    if ((t & 63) == 0) red[t >> 6] = m;
    __syncthreads();
    m = fmaxf(fmaxf(red[0], red[1]), fmaxf(red[2], red[3]));
    float e[8];
    e[0] = __expf(v0.x - m); e[1] = __expf(v0.y - m);
    e[2] = __expf(v0.z - m); e[3] = __expf(v0.w - m);
    e[4] = __expf(v1.x - m); e[5] = __expf(v1.y - m);
    e[6] = __expf(v1.z - m); e[7] = __expf(v1.w - m);
    float s = e[0] + e[1] + e[2] + e[3] + e[4] + e[5] + e[6] + e[7];
#pragma unroll
    for (int o = 32; o > 0; o >>= 1) s += __shfl_down(s, o, 64);
    if ((t & 63) == 0) red[4 + (t >> 6)] = s;
    __syncthreads();
    s = red[4] + red[5] + red[6] + red[7];
    float inv = 1.0f / s;
    f16x8 o;
#pragma unroll
    for (int j = 0; j < 8; ++j) o[j] = (f16)(e[j] * inv);
    reinterpret_cast<f16x8*>(rp)[t] = o;  // fp16 row at same base, stride 4096 elems
}

// ---------------------------------------------------------------- launch
extern "C" void kernel_launch(void* const* d_in, const int* in_sizes, int n_in,
                              void* d_out, int out_size, void* d_ws, size_t ws_size,
                              hipStream_t stream) {
    const float* x  = (const float*)d_in[0];
    const float* Wq = (const float*)d_in[1];
    const float* bq = (const float*)d_in[2];
    const float* Wk = (const float*)d_in[3];
    const float* bk = (const float*)d_in[4];
    const float* Wv = (const float*)d_in[5];
    const float* bv = (const float*)d_in[6];
    float* out = (float*)d_out;
    char* ws = (char*)d_ws;

    // Persistent-through-attention buffers
    f16* Q   = (f16*)(ws + 0);                       // 33,554,432 B
    f16* Kb  = (f16*)(ws + 33554432);                // 33,554,432 B
    f16* Vt  = (f16*)(ws + 67108864);                // 33,554,432 B
    float* S = (float*)(ws + 100663296);             // 134,217,728 B (ends 234,881,024)
    // Short-lived buffers, overlapping the (not-yet-written) S region
    f16* xh  = (f16*)(ws + 100663296);               // 33,554,432 B
    f16* wqt = (f16*)(ws + 134217728);               //  2,097,152 B
    f16* wkt = (f16*)(ws + 136314880);
    f16* wvt = (f16*)(ws + 138412032);               // ends 140,509,184

    cast_f32_f16<<<16384, 256, 0, stream>>>(x, xh);
    dim3 tb(32, 8);
    transpose_cast<<<dim3(32, 32), tb, 0, stream>>>(Wq, wqt, 1024, 1024);
    transpose_cast<<<dim3(32, 32), tb, 0, stream>>>(Wk, wkt, 1024, 1024);
    transpose_cast<<<dim3(32, 32), tb, 0, stream>>>(Wv, wvt, 1024, 1024);

    // projections: M=16384, N=1024, K=1024
    gemm_bt<0><<<dim3(8, 128, 1), 256, 0, stream>>>(xh, 0, 1024, wqt, 0, 1024, bq, Q, 0, 1024, 1024);
    gemm_bt<0><<<dim3(8, 128, 1), 256, 0, stream>>>(xh, 0, 1024, wkt, 0, 1024, bk, Kb, 0, 1024, 1024);
    gemm_bt<2><<<dim3(8, 128, 1), 256, 0, stream>>>(xh, 0, 1024, wvt, 0, 1024, bv, Vt, 0, 0, 1024);

    // S[b] = Q[b] @ K[b]^T : M=N=2048, K=1024, 8 batches (xh/Wt are dead now)
    gemm_bt<1><<<dim3(16, 16, 8), 256, 0, stream>>>(Q, 2048L * 1024, 1024,
                                                    Kb, 2048L * 1024, 1024, nullptr,
                                                    S, 2048L * 2048, 2048, 1024);

    softmax_rows<<<16384, 256, 0, stream>>>(S);

    // out[b] = P[b] @ V[b] : M=2048, N=1024, K=2048 ; P = fp16 alias of S, lda=4096
    gemm_bt<1><<<dim3(8, 16, 8), 256, 0, stream>>>((const f16*)S, 2048L * 4096, 4096,
                                                   Vt, 1024L * 2048, 2048, nullptr,
                                                   out, 2048L * 1024, 1024, 2048);
}

// Round 4
// 540.677 us; speedup vs baseline: 1.0155x; 1.0155x over previous
//
#include <hip/hip_runtime.h>
#include <hip/hip_bf16.h>
#include <stdint.h>

// SelfAttention: B=8, N=2048, D=DQ=DV=1024, fp32 in/out, fp16 MFMA internally.
// Round 3 -> 4: XOR-swizzled LDS layout in gemm_bt. The old layout (row
// stride 128 B) put all 16 lanes of a quad-group on the same 4-bank group ->
// 16-way conflict on every ds_read_b128 (SQ_LDS_BANK_CONFLICT=2.5e7, ~31% of
// QK^T cycles). Swizzle: LDS chunk j of row r holds global 16B chunk j^(r&7);
// fragment reads become conflict-free. global_load_lds staging coalescing is
// unchanged (permutation within the same 128 B segment).
//
// Workspace layout (224 MiB total; overlap exploits buffer lifetimes):
//   [0        , 32 MiB)   Q   (fp16)
//   [32 MiB   , 64 MiB)   K   (fp16)
//   [64 MiB   , 96 MiB)   Vt  (fp16, [b*1024+dv][seq])
//   [96 MiB   , 224 MiB)  S   (fp32, 8x2048x2048) -- written AFTER xh/Wt die
//     xh (32 MiB) + WqT/WkT/WvT (2 MiB each) overlap the S region.

typedef _Float16 f16;
typedef _Float16 f16x8 __attribute__((ext_vector_type(8)));
typedef _Float16 f16x4 __attribute__((ext_vector_type(4)));
typedef float f32x4 __attribute__((ext_vector_type(4)));

typedef __attribute__((address_space(3))) void lds_void;
typedef const __attribute__((address_space(1))) void gbl_void;

__device__ __forceinline__ void async16(void* l, const void* g) {
    __builtin_amdgcn_global_load_lds(
        reinterpret_cast<gbl_void*>(reinterpret_cast<uintptr_t>(g)),
        reinterpret_cast<lds_void*>(reinterpret_cast<uintptr_t>(l)),
        16, 0, 0);
}

// ---------------------------------------------------------------- cast x
__global__ __launch_bounds__(256) void cast_f32_f16(const float* __restrict__ x,
                                                    f16* __restrict__ y) {
    long i = (long)blockIdx.x * 256 + threadIdx.x;
    float4 v = reinterpret_cast<const float4*>(x)[i];
    f16x4 o = {(f16)v.x, (f16)v.y, (f16)v.z, (f16)v.w};
    reinterpret_cast<f16x4*>(y)[i] = o;
}

// ------------------------------------------------- transpose + cast W -> Wt
__global__ __launch_bounds__(256) void transpose_cast(const float* __restrict__ W,
                                                      f16* __restrict__ Wt,
                                                      int R, int C) {
    __shared__ float tile[32][33];
    int c0 = blockIdx.x * 32, r0 = blockIdx.y * 32;
    int tx = threadIdx.x, ty = threadIdx.y;
#pragma unroll
    for (int i = ty; i < 32; i += 8) tile[i][tx] = W[(long)(r0 + i) * C + c0 + tx];
    __syncthreads();
#pragma unroll
    for (int i = ty; i < 32; i += 8) Wt[(long)(c0 + i) * R + r0 + tx] = (f16)tile[tx][i];
}

// ---------------------------------------------------------------- GEMM
// C[m][n] = sum_k A[m][k] * Bt[n][k]  (+ bias[n])
// OM: 0 = fp16 row-major, 1 = fp32 row-major, 2 = fp16 V-transpose store
//     (OM2: row = b*2048 + seq, out[(b*1024 + n)*2048 + seq])
// LDS layout: row r (64 f16 = 8 chunks of 16 B); chunk j holds global chunk
// j ^ (r & 7).  Fragment read of global chunk c: LDS chunk c ^ (r & 7).
template <int OM>
__global__ __launch_bounds__(256) void gemm_bt(
    const f16* __restrict__ A, long sA, int lda,
    const f16* __restrict__ Bt, long sB, int ldb,
    const float* __restrict__ bias,
    void* __restrict__ out, long sO, int ldo, int K) {
    __shared__ f16 As[128 * 64];
    __shared__ f16 Bs[128 * 64];
    const int tid = threadIdx.x;
    const int lane = tid & 63;
    const int wv = tid >> 6;
    const int wm = (wv >> 1) * 64;
    const int wn = (wv & 1) * 64;
    const long mBase = (long)blockIdx.y * 128;
    const long nBase = (long)blockIdx.x * 128;
    A += (long)blockIdx.z * sA;
    Bt += (long)blockIdx.z * sB;

    f32x4 acc[4][4] = {};

    // Per-thread staging constants: thread u stages LDS chunk u (16 B) which
    // holds global (row u>>3, chunk (u&7) ^ (row&7)).
    const int sr = tid >> 3;                  // staged row (i-th iter adds 32)
    const int sj = tid & 7;                   // LDS chunk within row

    for (int k0 = 0; k0 < K; k0 += 64) {
#pragma unroll
        for (int i = 0; i < 4; ++i) {
            int u = i * 256 + tid;
            int r = sr + i * 32;
            int c = (sj ^ (r & 7)) * 8;       // swizzled global column
            async16((char*)As + u * 16, A + (mBase + r) * (long)lda + k0 + c);
            async16((char*)Bs + u * 16, Bt + (nBase + r) * (long)ldb + k0 + c);
        }
        __syncthreads();
#pragma unroll
        for (int ks = 0; ks < 2; ++ks) {
            f16x8 af[4], bfr[4];
            const int q8 = (lane >> 4) * 8 + ks * 32;     // global k-offset
            const int ra = wm + (lane & 15);
            const int rb = wn + (lane & 15);
            const int cc = (((q8 >> 3) ^ (lane & 7)) << 3);  // swizzled LDS col
#pragma unroll
            for (int t = 0; t < 4; ++t) {
                af[t] = *reinterpret_cast<const f16x8*>(&As[(ra + t * 16) * 64 + cc]);
                bfr[t] = *reinterpret_cast<const f16x8*>(&Bs[(rb + t * 16) * 64 + cc]);
            }
#pragma unroll
            for (int am = 0; am < 4; ++am)
#pragma unroll
                for (int an = 0; an < 4; ++an)
                    acc[am][an] = __builtin_amdgcn_mfma_f32_16x16x32_f16(
                        af[am], bfr[an], acc[am][an], 0, 0, 0);
        }
        __syncthreads();
    }

    const int rq = (lane >> 4) * 4;
    const int cl = lane & 15;
#pragma unroll
    for (int am = 0; am < 4; ++am) {
#pragma unroll
        for (int an = 0; an < 4; ++an) {
            long col = nBase + wn + an * 16 + cl;
            float bv = bias ? bias[col] : 0.0f;
#pragma unroll
            for (int r = 0; r < 4; ++r) {
                long row = mBase + wm + am * 16 + rq + r;
                float v = acc[am][an][r] + bv;
                if (OM == 0) {
                    ((f16*)out)[(long)blockIdx.z * sO + row * ldo + col] = (f16)v;
                } else if (OM == 1) {
                    ((float*)out)[(long)blockIdx.z * sO + row * ldo + col] = v;
                } else {
                    long bb = row >> 11, seq = row & 2047;
                    ((f16*)out)[(bb * 1024 + col) * 2048 + seq] = (f16)v;
                }
            }
        }
    }
}

// ---------------------------------------------------------------- softmax
// One block per row of S (16384 rows x 2048 fp32). Writes fp16 P in place.
__global__ __launch_bounds__(256) void softmax_rows(float* __restrict__ S) {
    const long row = blockIdx.x;
    float* rp = S + row * 2048;
    const int t = threadIdx.x;
    float4 v0 = reinterpret_cast<const float4*>(rp)[t * 2];
    float4 v1 = reinterpret_cast<const float4*>(rp)[t * 2 + 1];
    float m = fmaxf(fmaxf(fmaxf(v0.x, v0.y), fmaxf(v0.z, v0.w)),
                    fmaxf(fmaxf(v1.x, v1.y), fmaxf(v1.z, v1.w)));
#pragma unroll
    for (int o = 32; o > 0; o >>= 1) m = fmaxf(m, __shfl_down(m, o, 64));
    __shared__ float red[8];
    if ((t & 63) == 0) red[t >> 6] = m;
    __syncthreads();
    m = fmaxf(fmaxf(red[0], red[1]), fmaxf(red[2], red[3]));
    float e[8];
    e[0] = __expf(v0.x - m); e[1] = __expf(v0.y - m);
    e[2] = __expf(v0.z - m); e[3] = __expf(v0.w - m);
    e[4] = __expf(v1.x - m); e[5] = __expf(v1.y - m);
    e[6] = __expf(v1.z - m); e[7] = __expf(v1.w - m);
    float s = e[0] + e[1] + e[2] + e[3] + e[4] + e[5] + e[6] + e[7];
#pragma unroll
    for (int o = 32; o > 0; o >>= 1) s += __shfl_down(s, o, 64);
    if ((t & 63) == 0) red[4 + (t >> 6)] = s;
    __syncthreads();
    s = red[4] + red[5] + red[6] + red[7];
    float inv = 1.0f / s;
    f16x8 o;
#pragma unroll
    for (int j = 0; j < 8; ++j) o[j] = (f16)(e[j] * inv);
    reinterpret_cast<f16x8*>(rp)[t] = o;  // fp16 row at same base, stride 4096 elems
}

// ---------------------------------------------------------------- launch
extern "C" void kernel_launch(void* const* d_in, const int* in_sizes, int n_in,
                              void* d_out, int out_size, void* d_ws, size_t ws_size,
                              hipStream_t stream) {
    const float* x  = (const float*)d_in[0];
    const float* Wq = (const float*)d_in[1];
    const float* bq = (const float*)d_in[2];
    const float* Wk = (const float*)d_in[3];
    const float* bk = (const float*)d_in[4];
    const float* Wv = (const float*)d_in[5];
    const float* bv = (const float*)d_in[6];
    float* out = (float*)d_out;
    char* ws = (char*)d_ws;

    // Persistent-through-attention buffers
    f16* Q   = (f16*)(ws + 0);                       // 33,554,432 B
    f16* Kb  = (f16*)(ws + 33554432);                // 33,554,432 B
    f16* Vt  = (f16*)(ws + 67108864);                // 33,554,432 B
    float* S = (float*)(ws + 100663296);             // 134,217,728 B (ends 234,881,024)
    // Short-lived buffers, overlapping the (not-yet-written) S region
    f16* xh  = (f16*)(ws + 100663296);               // 33,554,432 B
    f16* wqt = (f16*)(ws + 134217728);               //  2,097,152 B
    f16* wkt = (f16*)(ws + 136314880);
    f16* wvt = (f16*)(ws + 138412032);               // ends 140,509,184

    cast_f32_f16<<<16384, 256, 0, stream>>>(x, xh);
    dim3 tb(32, 8);
    transpose_cast<<<dim3(32, 32), tb, 0, stream>>>(Wq, wqt, 1024, 1024);
    transpose_cast<<<dim3(32, 32), tb, 0, stream>>>(Wk, wkt, 1024, 1024);
    transpose_cast<<<dim3(32, 32), tb, 0, stream>>>(Wv, wvt, 1024, 1024);

    // projections: M=16384, N=1024, K=1024
    gemm_bt<0><<<dim3(8, 128, 1), 256, 0, stream>>>(xh, 0, 1024, wqt, 0, 1024, bq, Q, 0, 1024, 1024);
    gemm_bt<0><<<dim3(8, 128, 1), 256, 0, stream>>>(xh, 0, 1024, wkt, 0, 1024, bk, Kb, 0, 1024, 1024);
    gemm_bt<2><<<dim3(8, 128, 1), 256, 0, stream>>>(xh, 0, 1024, wvt, 0, 1024, bv, Vt, 0, 0, 1024);

    // S[b] = Q[b] @ K[b]^T : M=N=2048, K=1024, 8 batches (xh/Wt are dead now)
    gemm_bt<1><<<dim3(16, 16, 8), 256, 0, stream>>>(Q, 2048L * 1024, 1024,
                                                    Kb, 2048L * 1024, 1024, nullptr,
                                                    S, 2048L * 2048, 2048, 1024);

    softmax_rows<<<16384, 256, 0, stream>>>(S);

    // out[b] = P[b] @ V[b] : M=2048, N=1024, K=2048 ; P = fp16 alias of S, lda=4096
    gemm_bt<1><<<dim3(8, 16, 8), 256, 0, stream>>>((const f16*)S, 2048L * 4096, 4096,
                                                   Vt, 1024L * 2048, 2048, nullptr,
                                                   out, 2048L * 1024, 1024, 2048);
}

// Round 6
// 522.757 us; speedup vs baseline: 1.0503x; 1.0343x over previous
//
#include <hip/hip_runtime.h>
#include <hip/hip_bf16.h>
#include <stdint.h>

// SelfAttention: B=8, N=2048, D=DQ=DV=1024, fp32 in/out, fp16 MFMA internally.
// Round 5 -> 6: remove the P<->Q|K address alias (suspected stale-L2 hazard
// across XCDs: round-5 passed first call, diverged on replays). S is now fp16
// (64 MiB) so dense P gets its own region -- no address is written by two
// kernels in one call. Also halves S traffic. Keeps round-5 XCD decode +
// merged QKV projection.
//
// Workspace (224 MiB):
//   [0  , 32 MiB) Q   (fp16)
//   [32 , 64 MiB) K   (fp16)
//   [64 , 96 MiB) Vt  (fp16, [b*1024+dv][seq])
//   [96 ,160 MiB) S16 (fp16, 8x2048x2048)
//   [160,224 MiB) P   (fp16 dense, 16384x2048)
//   xh (32 MiB @96) + wt (6 MiB @128) overlap S16; both dead before QK^T
//   writes S16 (same liveness pattern as rounds 2-4, proven safe).

typedef _Float16 f16;
typedef _Float16 f16x8 __attribute__((ext_vector_type(8)));
typedef _Float16 f16x4 __attribute__((ext_vector_type(4)));
typedef float f32x4 __attribute__((ext_vector_type(4)));

typedef __attribute__((address_space(3))) void lds_void;
typedef const __attribute__((address_space(1))) void gbl_void;

__device__ __forceinline__ void async16(void* l, const void* g) {
    __builtin_amdgcn_global_load_lds(
        reinterpret_cast<gbl_void*>(reinterpret_cast<uintptr_t>(g)),
        reinterpret_cast<lds_void*>(reinterpret_cast<uintptr_t>(l)),
        16, 0, 0);
}

// ---------------------------------------------------------------- cast x
__global__ __launch_bounds__(256) void cast_f32_f16(const float* __restrict__ x,
                                                    f16* __restrict__ y) {
    long i = (long)blockIdx.x * 256 + threadIdx.x;
    float4 v = reinterpret_cast<const float4*>(x)[i];
    f16x4 o = {(f16)v.x, (f16)v.y, (f16)v.z, (f16)v.w};
    reinterpret_cast<f16x4*>(y)[i] = o;
}

// ------------------------------------- transpose + cast Wq|Wk|Wv -> wt[3072][1024]
__global__ __launch_bounds__(256) void transpose_cast3(const float* __restrict__ W0,
                                                       const float* __restrict__ W1,
                                                       const float* __restrict__ W2,
                                                       f16* __restrict__ wt) {
    const float* W = blockIdx.z == 0 ? W0 : blockIdx.z == 1 ? W1 : W2;
    f16* o = wt + (long)blockIdx.z * 1024 * 1024;
    __shared__ float tile[32][33];
    int c0 = blockIdx.x * 32, r0 = blockIdx.y * 32;
    int tx = threadIdx.x, ty = threadIdx.y;
#pragma unroll
    for (int i = ty; i < 32; i += 8) tile[i][tx] = W[(long)(r0 + i) * 1024 + c0 + tx];
    __syncthreads();
#pragma unroll
    for (int i = ty; i < 32; i += 8) o[(long)(c0 + i) * 1024 + r0 + tx] = (f16)tile[tx][i];
}

// ------------------------------------------------------------ GEMM core macro
// LDS layout: row r = 8 chunks of 16B; chunk j holds global chunk j^(r&7)
// (bank-conflict-free ds_read_b128, staging coalescing unchanged).
#define GEMM_CORE(A_, lda_, B_, ldb_, K_)                                         \
    f32x4 acc[4][4] = {};                                                         \
    const int sr = tid >> 3;                                                      \
    const int sj = tid & 7;                                                       \
    for (int k0 = 0; k0 < (K_); k0 += 64) {                                       \
        _Pragma("unroll") for (int i = 0; i < 4; ++i) {                           \
            int u = i * 256 + tid;                                                \
            int r = sr + i * 32;                                                  \
            int c = (sj ^ (r & 7)) * 8;                                           \
            async16((char*)As + u * 16, (A_) + (mBase + r) * (long)(lda_) + k0 + c); \
            async16((char*)Bs + u * 16, (B_) + (nBase + r) * (long)(ldb_) + k0 + c); \
        }                                                                         \
        __syncthreads();                                                          \
        _Pragma("unroll") for (int ks = 0; ks < 2; ++ks) {                        \
            f16x8 af[4], bfr[4];                                                  \
            const int q8 = (lane >> 4) * 8 + ks * 32;                             \
            const int ra = wm + (lane & 15);                                      \
            const int rb = wn + (lane & 15);                                      \
            const int cc = (((q8 >> 3) ^ (lane & 7)) << 3);                       \
            _Pragma("unroll") for (int t = 0; t < 4; ++t) {                       \
                af[t] = *reinterpret_cast<const f16x8*>(&As[(ra + t * 16) * 64 + cc]); \
                bfr[t] = *reinterpret_cast<const f16x8*>(&Bs[(rb + t * 16) * 64 + cc]); \
            }                                                                     \
            _Pragma("unroll") for (int am = 0; am < 4; ++am)                      \
                _Pragma("unroll") for (int an = 0; an < 4; ++an)                  \
                    acc[am][an] = __builtin_amdgcn_mfma_f32_16x16x32_f16(         \
                        af[am], bfr[an], acc[am][an], 0, 0, 0);                   \
        }                                                                         \
        __syncthreads();                                                          \
    }

#define GEMM_PRELUDE                                                              \
    __shared__ f16 As[128 * 64];                                                  \
    __shared__ f16 Bs[128 * 64];                                                  \
    const int tid = threadIdx.x;                                                  \
    const int lane = tid & 63;                                                    \
    const int wv = tid >> 6;                                                      \
    const int wm = (wv >> 1) * 64;                                                \
    const int wn = (wv & 1) * 64;

// ---------------------------------------------------- batched GEMM (QK^T / PV)
// C[z][m][n] = sum_k A[z][m][k] * Bt[z][n][k].
// DEC 1 = QK^T (16x16 tiles/batch, fp16 out); DEC 2 = PV (8x16, fp32 out).
// xcd = linear%8 owns one batch (L2 locality heuristic only).
template <int DEC>
__global__ __launch_bounds__(256) void gemm_bt(
    const f16* __restrict__ A, long sA, int lda,
    const f16* __restrict__ Bt, long sB, int ldb,
    void* __restrict__ outv, long sO, int ldo, int K) {
    GEMM_PRELUDE
    const int L = blockIdx.x;
    const int xcd = L & 7, j = L >> 3;
    int bx, by;
    if (DEC == 1) { bx = j & 15; by = j >> 4; }     // 2048 blocks
    else          { bx = j & 7;  by = j >> 3; }     // 1024 blocks
    const long mBase = (long)by * 128;
    const long nBase = (long)bx * 128;
    A += (long)xcd * sA;
    Bt += (long)xcd * sB;

    GEMM_CORE(A, lda, Bt, ldb, K)

    const int rq = (lane >> 4) * 4;
    const int cl = lane & 15;
#pragma unroll
    for (int am = 0; am < 4; ++am)
#pragma unroll
        for (int an = 0; an < 4; ++an) {
            long col = nBase + wn + an * 16 + cl;
#pragma unroll
            for (int r = 0; r < 4; ++r) {
                long row = mBase + wm + am * 16 + rq + r;
                if (DEC == 1) {
                    ((f16*)outv)[(long)xcd * sO + row * ldo + col] = (f16)acc[am][an][r];
                } else {
                    ((float*)outv)[(long)xcd * sO + row * ldo + col] = acc[am][an][r];
                }
            }
        }
}

// ------------------------------------------- merged QKV projection GEMM
// M=16384 (b*2048+seq), N=3072 (seg 0=Q,1=K,2=V), K=1024. 3072 blocks;
// xcd owns a contiguous 16-tile M-slice (one batch's rows).
__global__ __launch_bounds__(256) void gemm_qkv(
    const f16* __restrict__ xh, const f16* __restrict__ wt,
    const float* __restrict__ bq, const float* __restrict__ bk,
    const float* __restrict__ bv,
    f16* __restrict__ Q, f16* __restrict__ Kb, f16* __restrict__ Vt) {
    GEMM_PRELUDE
    const int L = blockIdx.x;
    const int xcd = L & 7, j = L >> 3;              // j in [0,384)
    const int bx = j % 24;
    const int by = xcd * 16 + j / 24;
    const long mBase = (long)by * 128;
    const long nBase = (long)bx * 128;

    GEMM_CORE(xh, 1024, wt, 1024, 1024)

    const int seg = (int)(nBase >> 10);             // wave-uniform
    const float* bias = seg == 0 ? bq : seg == 1 ? bk : bv;
    f16* outQK = seg == 0 ? Q : Kb;
    const int rq = (lane >> 4) * 4;
    const int cl = lane & 15;
#pragma unroll
    for (int am = 0; am < 4; ++am)
#pragma unroll
        for (int an = 0; an < 4; ++an) {
            long col = nBase + wn + an * 16 + cl;
            long c = col & 1023;
            float bvv = bias[c];
#pragma unroll
            for (int r = 0; r < 4; ++r) {
                long row = mBase + wm + am * 16 + rq + r;
                float v = acc[am][an][r] + bvv;
                if (seg < 2) {
                    outQK[row * 1024 + c] = (f16)v;
                } else {
                    long bb = row >> 11, seq = row & 2047;
                    Vt[(bb * 1024 + c) * 2048 + seq] = (f16)v;
                }
            }
        }
}

// ---------------------------------------------------------------- softmax
// One block per row (16384 rows x 2048 fp16 logits). Reads S16, writes P.
__global__ __launch_bounds__(256) void softmax_rows(const f16* __restrict__ S,
                                                    f16* __restrict__ P) {
    const long row = blockIdx.x;
    const int t = threadIdx.x;
    f16x8 a = reinterpret_cast<const f16x8*>(S + row * 2048)[t];
    float e[8];
    float m = -1e30f;
#pragma unroll
    for (int j = 0; j < 8; ++j) { e[j] = (float)a[j]; m = fmaxf(m, e[j]); }
#pragma unroll
    for (int o = 32; o > 0; o >>= 1) m = fmaxf(m, __shfl_down(m, o, 64));
    __shared__ float red[8];
    if ((t & 63) == 0) red[t >> 6] = m;
    __syncthreads();
    m = fmaxf(fmaxf(red[0], red[1]), fmaxf(red[2], red[3]));
    float s = 0.0f;
#pragma unroll
    for (int j = 0; j < 8; ++j) { e[j] = __expf(e[j] - m); s += e[j]; }
#pragma unroll
    for (int o = 32; o > 0; o >>= 1) s += __shfl_down(s, o, 64);
    if ((t & 63) == 0) red[4 + (t >> 6)] = s;
    __syncthreads();
    s = red[4] + red[5] + red[6] + red[7];
    float inv = 1.0f / s;
    f16x8 o;
#pragma unroll
    for (int j = 0; j < 8; ++j) o[j] = (f16)(e[j] * inv);
    reinterpret_cast<f16x8*>(P + row * 2048)[t] = o;
}

// ---------------------------------------------------------------- launch
extern "C" void kernel_launch(void* const* d_in, const int* in_sizes, int n_in,
                              void* d_out, int out_size, void* d_ws, size_t ws_size,
                              hipStream_t stream) {
    const float* x  = (const float*)d_in[0];
    const float* Wq = (const float*)d_in[1];
    const float* bq = (const float*)d_in[2];
    const float* Wk = (const float*)d_in[3];
    const float* bk = (const float*)d_in[4];
    const float* Wv = (const float*)d_in[5];
    const float* bv = (const float*)d_in[6];
    float* out = (float*)d_out;
    char* ws = (char*)d_ws;

    f16* Q   = (f16*)(ws + 0);                       // 32 MiB
    f16* Kb  = (f16*)(ws + 33554432);                // 32 MiB
    f16* Vt  = (f16*)(ws + 67108864);                // 32 MiB
    f16* S16 = (f16*)(ws + 100663296);               // 64 MiB (fp16 logits)
    f16* P   = (f16*)(ws + 167772160);               // 64 MiB (ends 224 MiB)
    f16* xh  = (f16*)(ws + 100663296);               // 32 MiB (dead before S16)
    f16* wt  = (f16*)(ws + 134217728);               //  6 MiB (dead before S16)

    cast_f32_f16<<<16384, 256, 0, stream>>>(x, xh);
    transpose_cast3<<<dim3(32, 32, 3), dim3(32, 8), 0, stream>>>(Wq, Wk, Wv, wt);

    // merged projections: M=16384, N=3072, K=1024 (3072 blocks)
    gemm_qkv<<<3072, 256, 0, stream>>>(xh, wt, bq, bk, bv, Q, Kb, Vt);

    // S16[b] = Q[b] @ K[b]^T : M=N=2048, K=1024, batch=xcd (2048 blocks, fp16 out)
    gemm_bt<1><<<2048, 256, 0, stream>>>(Q, 2048L * 1024, 1024,
                                         Kb, 2048L * 1024, 1024,
                                         S16, 2048L * 2048, 2048, 1024);

    softmax_rows<<<16384, 256, 0, stream>>>(S16, P);

    // out[b] = P[b] @ V[b] : M=2048, N=1024, K=2048, batch=xcd (1024 blocks)
    gemm_bt<2><<<1024, 256, 0, stream>>>(P, 2048L * 2048, 2048,
                                         Vt, 1024L * 2048, 2048,
                                         out, 2048L * 1024, 1024, 2048);
}

// Round 7
// 475.348 us; speedup vs baseline: 1.1550x; 1.0997x over previous
//
#include <hip/hip_runtime.h>
#include <hip/hip_bf16.h>
#include <stdint.h>

// SelfAttention: B=8, N=2048, D=DQ=DV=1024, fp32 in/out, fp16 MFMA internally.
// Round 6 -> 7: balanced 8Mx4N supertile decode inside each XCD's block
// range (all 3 GEMMs). Round-6's N-fast inner order kept 24 B-tiles (6 MB)
// live per XCD -> L2 thrash (gemm_qkv FETCH 278 MB vs 38 MB input, MfmaUtil
// 21%). A supertile's 32 blocks share 8 A-tiles + 4 B-tiles (~3 MB) -> L2
// reuse x4/x8; M-super-fast ordering keeps each 4-N B-group resident across
// M-supers.
//
// Workspace (224 MiB):
//   [0  , 32 MiB) Q   (fp16)
//   [32 , 64 MiB) K   (fp16)
//   [64 , 96 MiB) Vt  (fp16, [b*1024+dv][seq])
//   [96 ,160 MiB) S16 (fp16, 8x2048x2048)
//   [160,224 MiB) P   (fp16 dense, 16384x2048)
//   xh (32 MiB @96) + wt (6 MiB @128) overlap S16; dead before QK^T writes.

typedef _Float16 f16;
typedef _Float16 f16x8 __attribute__((ext_vector_type(8)));
typedef _Float16 f16x4 __attribute__((ext_vector_type(4)));
typedef float f32x4 __attribute__((ext_vector_type(4)));

typedef __attribute__((address_space(3))) void lds_void;
typedef const __attribute__((address_space(1))) void gbl_void;

__device__ __forceinline__ void async16(void* l, const void* g) {
    __builtin_amdgcn_global_load_lds(
        reinterpret_cast<gbl_void*>(reinterpret_cast<uintptr_t>(g)),
        reinterpret_cast<lds_void*>(reinterpret_cast<uintptr_t>(l)),
        16, 0, 0);
}

// ---------------------------------------------------------------- cast x
__global__ __launch_bounds__(256) void cast_f32_f16(const float* __restrict__ x,
                                                    f16* __restrict__ y) {
    long i = (long)blockIdx.x * 256 + threadIdx.x;
    float4 v = reinterpret_cast<const float4*>(x)[i];
    f16x4 o = {(f16)v.x, (f16)v.y, (f16)v.z, (f16)v.w};
    reinterpret_cast<f16x4*>(y)[i] = o;
}

// ------------------------------------- transpose + cast Wq|Wk|Wv -> wt[3072][1024]
__global__ __launch_bounds__(256) void transpose_cast3(const float* __restrict__ W0,
                                                       const float* __restrict__ W1,
                                                       const float* __restrict__ W2,
                                                       f16* __restrict__ wt) {
    const float* W = blockIdx.z == 0 ? W0 : blockIdx.z == 1 ? W1 : W2;
    f16* o = wt + (long)blockIdx.z * 1024 * 1024;
    __shared__ float tile[32][33];
    int c0 = blockIdx.x * 32, r0 = blockIdx.y * 32;
    int tx = threadIdx.x, ty = threadIdx.y;
#pragma unroll
    for (int i = ty; i < 32; i += 8) tile[i][tx] = W[(long)(r0 + i) * 1024 + c0 + tx];
    __syncthreads();
#pragma unroll
    for (int i = ty; i < 32; i += 8) o[(long)(c0 + i) * 1024 + r0 + tx] = (f16)tile[tx][i];
}

// ------------------------------------------------------------ GEMM core macro
// LDS layout: row r = 8 chunks of 16B; chunk j holds global chunk j^(r&7)
// (bank-conflict-free ds_read_b128, staging coalescing unchanged).
#define GEMM_CORE(A_, lda_, B_, ldb_, K_)                                         \
    f32x4 acc[4][4] = {};                                                         \
    const int sr = tid >> 3;                                                      \
    const int sj = tid & 7;                                                       \
    for (int k0 = 0; k0 < (K_); k0 += 64) {                                       \
        _Pragma("unroll") for (int i = 0; i < 4; ++i) {                           \
            int u = i * 256 + tid;                                                \
            int r = sr + i * 32;                                                  \
            int c = (sj ^ (r & 7)) * 8;                                           \
            async16((char*)As + u * 16, (A_) + (mBase + r) * (long)(lda_) + k0 + c); \
            async16((char*)Bs + u * 16, (B_) + (nBase + r) * (long)(ldb_) + k0 + c); \
        }                                                                         \
        __syncthreads();                                                          \
        _Pragma("unroll") for (int ks = 0; ks < 2; ++ks) {                        \
            f16x8 af[4], bfr[4];                                                  \
            const int q8 = (lane >> 4) * 8 + ks * 32;                             \
            const int ra = wm + (lane & 15);                                      \
            const int rb = wn + (lane & 15);                                      \
            const int cc = (((q8 >> 3) ^ (lane & 7)) << 3);                       \
            _Pragma("unroll") for (int t = 0; t < 4; ++t) {                       \
                af[t] = *reinterpret_cast<const f16x8*>(&As[(ra + t * 16) * 64 + cc]); \
                bfr[t] = *reinterpret_cast<const f16x8*>(&Bs[(rb + t * 16) * 64 + cc]); \
            }                                                                     \
            _Pragma("unroll") for (int am = 0; am < 4; ++am)                      \
                _Pragma("unroll") for (int an = 0; an < 4; ++an)                  \
                    acc[am][an] = __builtin_amdgcn_mfma_f32_16x16x32_f16(         \
                        af[am], bfr[an], acc[am][an], 0, 0, 0);                   \
        }                                                                         \
        __syncthreads();                                                          \
    }

#define GEMM_PRELUDE                                                              \
    __shared__ f16 As[128 * 64];                                                  \
    __shared__ f16 Bs[128 * 64];                                                  \
    const int tid = threadIdx.x;                                                  \
    const int lane = tid & 63;                                                    \
    const int wv = tid >> 6;                                                      \
    const int wm = (wv >> 1) * 64;                                                \
    const int wn = (wv & 1) * 64;

// Supertile decode: within an XCD's block range, j -> (my, nx) in 8Mx4N
// supertiles, M-super-fast. my in [0,MT), nx in [0,NT); MT,NT divisible 8,4.
#define SUPER_DECODE(j_, MT_, my_, nx_)                                           \
    {                                                                             \
        int w_ = (j_) & 31, s_ = (j_) >> 5;                                       \
        int sm_ = s_ % ((MT_) / 8), sn_ = s_ / ((MT_) / 8);                       \
        my_ = sm_ * 8 + (w_ & 7);                                                 \
        nx_ = sn_ * 4 + (w_ >> 3);                                                \
    }

// ---------------------------------------------------- batched GEMM (QK^T / PV)
// C[z][m][n] = sum_k A[z][m][k] * Bt[z][n][k].
// DEC 1 = QK^T (16Mx16N tiles/batch, fp16 out); DEC 2 = PV (16Mx8N, fp32 out).
// xcd = linear%8 owns one batch (L2 locality heuristic only).
template <int DEC>
__global__ __launch_bounds__(256) void gemm_bt(
    const f16* __restrict__ A, long sA, int lda,
    const f16* __restrict__ Bt, long sB, int ldb,
    void* __restrict__ outv, long sO, int ldo, int K) {
    GEMM_PRELUDE
    const int L = blockIdx.x;
    const int xcd = L & 7, j = L >> 3;
    int by, bx;
    SUPER_DECODE(j, 16, by, bx)                     // DEC1: j<256; DEC2: j<128
    const long mBase = (long)by * 128;
    const long nBase = (long)bx * 128;
    A += (long)xcd * sA;
    Bt += (long)xcd * sB;

    GEMM_CORE(A, lda, Bt, ldb, K)

    const int rq = (lane >> 4) * 4;
    const int cl = lane & 15;
#pragma unroll
    for (int am = 0; am < 4; ++am)
#pragma unroll
        for (int an = 0; an < 4; ++an) {
            long col = nBase + wn + an * 16 + cl;
#pragma unroll
            for (int r = 0; r < 4; ++r) {
                long row = mBase + wm + am * 16 + rq + r;
                if (DEC == 1) {
                    ((f16*)outv)[(long)xcd * sO + row * ldo + col] = (f16)acc[am][an][r];
                } else {
                    ((float*)outv)[(long)xcd * sO + row * ldo + col] = acc[am][an][r];
                }
            }
        }
}

// ------------------------------------------- merged QKV projection GEMM
// M=16384 (b*2048+seq), N=3072 (seg 0=Q,1=K,2=V), K=1024. 3072 blocks;
// xcd owns a contiguous 16-M-tile slice (one batch), 16Mx24N tiles.
__global__ __launch_bounds__(256) void gemm_qkv(
    const f16* __restrict__ xh, const f16* __restrict__ wt,
    const float* __restrict__ bq, const float* __restrict__ bk,
    const float* __restrict__ bv,
    f16* __restrict__ Q, f16* __restrict__ Kb, f16* __restrict__ Vt) {
    GEMM_PRELUDE
    const int L = blockIdx.x;
    const int xcd = L & 7, j = L >> 3;              // j in [0,384)
    int my, bx;
    SUPER_DECODE(j, 16, my, bx)
    const int by = xcd * 16 + my;
    const long mBase = (long)by * 128;
    const long nBase = (long)bx * 128;

    GEMM_CORE(xh, 1024, wt, 1024, 1024)

    const int seg = (int)(nBase >> 10);             // wave-uniform
    const float* bias = seg == 0 ? bq : seg == 1 ? bk : bv;
    f16* outQK = seg == 0 ? Q : Kb;
    const int rq = (lane >> 4) * 4;
    const int cl = lane & 15;
#pragma unroll
    for (int am = 0; am < 4; ++am)
#pragma unroll
        for (int an = 0; an < 4; ++an) {
            long col = nBase + wn + an * 16 + cl;
            long c = col & 1023;
            float bvv = bias[c];
#pragma unroll
            for (int r = 0; r < 4; ++r) {
                long row = mBase + wm + am * 16 + rq + r;
                float v = acc[am][an][r] + bvv;
                if (seg < 2) {
                    outQK[row * 1024 + c] = (f16)v;
                } else {
                    long bb = row >> 11, seq = row & 2047;
                    Vt[(bb * 1024 + c) * 2048 + seq] = (f16)v;
                }
            }
        }
}

// ---------------------------------------------------------------- softmax
// One block per row (16384 rows x 2048 fp16 logits). Reads S16, writes P.
__global__ __launch_bounds__(256) void softmax_rows(const f16* __restrict__ S,
                                                    f16* __restrict__ P) {
    const long row = blockIdx.x;
    const int t = threadIdx.x;
    f16x8 a = reinterpret_cast<const f16x8*>(S + row * 2048)[t];
    float e[8];
    float m = -1e30f;
#pragma unroll
    for (int j = 0; j < 8; ++j) { e[j] = (float)a[j]; m = fmaxf(m, e[j]); }
#pragma unroll
    for (int o = 32; o > 0; o >>= 1) m = fmaxf(m, __shfl_down(m, o, 64));
    __shared__ float red[8];
    if ((t & 63) == 0) red[t >> 6] = m;
    __syncthreads();
    m = fmaxf(fmaxf(red[0], red[1]), fmaxf(red[2], red[3]));
    float s = 0.0f;
#pragma unroll
    for (int j = 0; j < 8; ++j) { e[j] = __expf(e[j] - m); s += e[j]; }
#pragma unroll
    for (int o = 32; o > 0; o >>= 1) s += __shfl_down(s, o, 64);
    if ((t & 63) == 0) red[4 + (t >> 6)] = s;
    __syncthreads();
    s = red[4] + red[5] + red[6] + red[7];
    float inv = 1.0f / s;
    f16x8 o;
#pragma unroll
    for (int j = 0; j < 8; ++j) o[j] = (f16)(e[j] * inv);
    reinterpret_cast<f16x8*>(P + row * 2048)[t] = o;
}

// ---------------------------------------------------------------- launch
extern "C" void kernel_launch(void* const* d_in, const int* in_sizes, int n_in,
                              void* d_out, int out_size, void* d_ws, size_t ws_size,
                              hipStream_t stream) {
    const float* x  = (const float*)d_in[0];
    const float* Wq = (const float*)d_in[1];
    const float* bq = (const float*)d_in[2];
    const float* Wk = (const float*)d_in[3];
    const float* bk = (const float*)d_in[4];
    const float* Wv = (const float*)d_in[5];
    const float* bv = (const float*)d_in[6];
    float* out = (float*)d_out;
    char* ws = (char*)d_ws;

    f16* Q   = (f16*)(ws + 0);                       // 32 MiB
    f16* Kb  = (f16*)(ws + 33554432);                // 32 MiB
    f16* Vt  = (f16*)(ws + 67108864);                // 32 MiB
    f16* S16 = (f16*)(ws + 100663296);               // 64 MiB (fp16 logits)
    f16* P   = (f16*)(ws + 167772160);               // 64 MiB (ends 224 MiB)
    f16* xh  = (f16*)(ws + 100663296);               // 32 MiB (dead before S16)
    f16* wt  = (f16*)(ws + 134217728);               //  6 MiB (dead before S16)

    cast_f32_f16<<<16384, 256, 0, stream>>>(x, xh);
    transpose_cast3<<<dim3(32, 32, 3), dim3(32, 8), 0, stream>>>(Wq, Wk, Wv, wt);

    // merged projections: M=16384, N=3072, K=1024 (3072 blocks)
    gemm_qkv<<<3072, 256, 0, stream>>>(xh, wt, bq, bk, bv, Q, Kb, Vt);

    // S16[b] = Q[b] @ K[b]^T : M=N=2048, K=1024, batch=xcd (2048 blocks, fp16 out)
    gemm_bt<1><<<2048, 256, 0, stream>>>(Q, 2048L * 1024, 1024,
                                         Kb, 2048L * 1024, 1024,
                                         S16, 2048L * 2048, 2048, 1024);

    softmax_rows<<<16384, 256, 0, stream>>>(S16, P);

    // out[b] = P[b] @ V[b] : M=2048, N=1024, K=2048, batch=xcd (1024 blocks)
    gemm_bt<2><<<1024, 256, 0, stream>>>(P, 2048L * 2048, 2048,
                                         Vt, 1024L * 2048, 2048,
                                         out, 2048L * 1024, 1024, 2048);
}